// Round 1
// 437.880 us; speedup vs baseline: 1.0192x; 1.0192x over previous
//
#include <hip/hip_runtime.h>
#include <cstdint>

#define B_ 4
#define T_ 2048
#define C_ 2048
#define H_ 16
#define HKV_ 4
#define D_ 128

typedef unsigned short u16;
typedef __bf16 bf16x8 __attribute__((ext_vector_type(8)));
typedef float f32x4 __attribute__((ext_vector_type(4)));
typedef float f32x16 __attribute__((ext_vector_type(16)));

typedef __attribute__((address_space(1))) const void gvoid;
typedef __attribute__((address_space(3))) void lvoid;

static __device__ __forceinline__ void async_cp16(const u16* g, u16* l) {
  __builtin_amdgcn_global_load_lds((gvoid*)g, (lvoid*)l, 16, 0, 0);
}

static __device__ __forceinline__ u16 f2bf(float f) {
  unsigned int x = __builtin_bit_cast(unsigned int, f);
  x += 0x7fffu + ((x >> 16) & 1u);
  return (u16)(x >> 16);
}

// ---------------- prep: cast x fp32->bf16 (blocks 0..4095) + weight transposes ----------------
__global__ void prep_kernel(const float* __restrict__ x, const float* __restrict__ Wq,
                            const float* __restrict__ Wk, const float* __restrict__ Wv,
                            const float* __restrict__ Wc, u16* __restrict__ xb,
                            u16* __restrict__ Wcat, u16* __restrict__ WcT) {
  __shared__ float tile[64][65];
  int tb = blockIdx.x, tid = threadIdx.x;
  if (tb < 4096) {                       // cast: 4096 blocks x 1024 float4
    const float4* in4 = (const float4*)x;
#pragma unroll
    for (int j = 0; j < 4; j++) {
      int i = tb * 1024 + j * 256 + tid;
      float4 v = in4[i];
      ushort4 o;
      o.x = f2bf(v.x); o.y = f2bf(v.y); o.z = f2bf(v.z); o.w = f2bf(v.w);
      ((ushort4*)xb)[i] = o;
    }
    return;
  }
  int tb2 = tb - 4096;
  const float* W; u16* WT; int Nw, t;
  if (tb2 < 1024)      { W = Wq; WT = Wcat;                       Nw = 2048; t = tb2; }
  else if (tb2 < 1280) { W = Wk; WT = Wcat + (size_t)2048 * 2048; Nw = 512;  t = tb2 - 1024; }
  else if (tb2 < 1536) { W = Wv; WT = Wcat + (size_t)2560 * 2048; Nw = 512;  t = tb2 - 1280; }
  else                 { W = Wc; WT = WcT;                        Nw = 2048; t = tb2 - 1536; }
  int ntiles = Nw >> 6;
  int n0 = (t % ntiles) * 64, k0 = (t / ntiles) * 64;
#pragma unroll
  for (int i = 0; i < 16; i++) {
    int idx = i * 256 + tid;
    int r = idx >> 6, c = idx & 63;
    tile[r][c] = W[(size_t)(k0 + r) * Nw + n0 + c];
  }
  __syncthreads();
#pragma unroll
  for (int i = 0; i < 16; i++) {
    int idx = i * 256 + tid;
    int r = idx >> 6, c = idx & 63;
    WT[(size_t)(n0 + r) * 2048 + k0 + c] = f2bf(tile[c][r]);
  }
}

// ================= 8-phase 256x256 GEMM core (T2+T3+T4+T5, plain HIP) =================
// C(256m x 256n) += A[m0..m0+256)[K=2048] * B[n0..n0+256)[K]^T, both operands row-major [rows][K].
// 512 threads = 8 waves (2 m-waves x 4 n-waves); per-wave output 128x64 = acc[8][4] f32x4.
// LDS: 2 buffers x (A 256x64 | B 256x64) bf16 = 131072 B (dynamic).
// Per K-tile, 4 phases, quadrant order (0,0),(1,0),(1,1),(0,1); ds reads 12/8/4/0
// (A-frags cached across the tile, B per n-half). Stage order per tile t:
//   ph0: B-lo(t+1)  ph1: B-hi(t+1)  ph2: A-lo(t+2)  ph3: A-hi(t+2)
// chosen so a region staged at phase p was last ds_read at phase <= p-1 (barrier-pair
// separated => race-free). vmcnt(4) once per tile (2 half-tiles in flight), vmcnt(0)
// only at t=30. Never drains in the main loop (T4). setprio(1) around MFMA (T5).
static __device__ __forceinline__ void core8(const u16* __restrict__ Aop,
                                             const u16* __restrict__ Bop,
                                             int m0, int n0, char* smem,
                                             f32x4 (&acc)[8][4]) {
  const int tid = threadIdx.x;
  const int lane = tid & 63, w = tid >> 6;
  const int wm = w >> 2, wn = w & 3;
  const int quad = lane >> 4, lo = lane & 15;
  // staging: thread covers rows (tid>>3) and (tid>>3)+64 of each 128x64 half-tile,
  // 16B chunk (tid&7), global source pre-swizzled chunk^(row&7), LDS dest linear.
  const int sr = tid >> 3, sc = tid & 7;
  const int gcol = (sc ^ (sr & 7)) << 3;
  const u16* sA = Aop + (size_t)(m0 + sr) * 2048 + gcol;
  const u16* sB = Bop + (size_t)(n0 + sr) * 2048 + gcol;
  // read-side swizzled chunk byte offsets (row&7 == lo&7 for all frags)
  const int c0 = ((quad ^ (lo & 7)) << 4);
  const int c1 = (((4 + quad) ^ (lo & 7)) << 4);
  char* rA = smem + (wm * 128 + lo) * 128;           // + boff + mfrag*2048 + c{0,1}
  char* rB = smem + 32768 + (wn * 64 + lo) * 128;    // + boff + nfrag*2048 + c{0,1}
  bf16x8 Af[8][2], Bf[2][2];

#define STAGE8(u, j)                                                                         \
  do {                                                                                       \
    if ((u) < 32) {                                                                          \
      const u16* s_ = (((j) & 2) ? sB : sA) + (((j) & 1) ? (size_t)262144 : (size_t)0) +     \
                      (size_t)(u) * 64;                                                      \
      char* d_ = smem + (((u) & 1) << 16) + (((j) & 2) << 14) + (((j) & 1) << 14) + tid * 16;\
      async_cp16(s_, (u16*)d_);                                                              \
      async_cp16(s_ + 131072, (u16*)(d_ + 8192));                                            \
    }                                                                                        \
  } while (0)

#define RDA8(boff, mlo)                                                                      \
  do {                                                                                       \
    _Pragma("unroll") for (int m_ = 0; m_ < 4; m_++) {                                       \
      char* p_ = rA + (boff) + ((mlo) + m_) * 2048;                                          \
      Af[(mlo) + m_][0] = *(const bf16x8*)(p_ + c0);                                         \
      Af[(mlo) + m_][1] = *(const bf16x8*)(p_ + c1);                                         \
    }                                                                                        \
  } while (0)

#define RDB8(boff, nlo)                                                                      \
  do {                                                                                       \
    _Pragma("unroll") for (int n_ = 0; n_ < 2; n_++) {                                       \
      char* p_ = rB + (boff) + ((nlo) + n_) * 2048;                                          \
      Bf[n_][0] = *(const bf16x8*)(p_ + c0);                                                 \
      Bf[n_][1] = *(const bf16x8*)(p_ + c1);                                                 \
    }                                                                                        \
  } while (0)

#define MM8(mlo, nlo)                                                                        \
  do {                                                                                       \
    __builtin_amdgcn_s_setprio(1);                                                           \
    _Pragma("unroll") for (int m_ = 0; m_ < 4; m_++)                                         \
      _Pragma("unroll") for (int n_ = 0; n_ < 2; n_++)                                       \
        _Pragma("unroll") for (int k_ = 0; k_ < 2; k_++)                                     \
          acc[(mlo) + m_][(nlo) + n_] = __builtin_amdgcn_mfma_f32_16x16x32_bf16(             \
              Af[(mlo) + m_][k_], Bf[n_][k_], acc[(mlo) + m_][(nlo) + n_], 0, 0, 0);         \
    __builtin_amdgcn_s_setprio(0);                                                           \
  } while (0)

#define BAR8() __builtin_amdgcn_s_barrier()
#define LGKM0() asm volatile("s_waitcnt lgkmcnt(0)" ::: "memory")

  // prologue: tile0 complete + A halves of tile1; wait tile0 landed (4 loads = 2 halves out)
  STAGE8(0, 0); STAGE8(0, 1); STAGE8(0, 2); STAGE8(0, 3);
  STAGE8(1, 0); STAGE8(1, 1);
  asm volatile("s_waitcnt vmcnt(4)" ::: "memory");
  BAR8();

#pragma unroll 1
  for (int t = 0; t < 32; t++) {
    const int boff = (t & 1) << 16;
    // phase 0: quadrant (m0-3, n0-1)
    RDA8(boff, 0); RDB8(boff, 0);
    STAGE8(t + 1, 2);
    BAR8(); LGKM0();
    MM8(0, 0);
    BAR8();
    // phase 1: quadrant (m4-7, n0-1)
    RDA8(boff, 4);
    STAGE8(t + 1, 3);
    BAR8(); LGKM0();
    MM8(4, 0);
    BAR8();
    // phase 2: quadrant (m4-7, n2-3)
    RDB8(boff, 2);
    STAGE8(t + 2, 0);
    BAR8(); LGKM0();
    MM8(4, 2);
    BAR8();
    // phase 3: quadrant (m0-3, n2-3); counted vmcnt once per tile
    STAGE8(t + 2, 1);
    if (t < 30) {
      asm volatile("s_waitcnt vmcnt(4)" ::: "memory");
    } else if (t == 30) {
      asm volatile("s_waitcnt vmcnt(0)" ::: "memory");
    }
    BAR8(); LGKM0();
    MM8(0, 2);
    BAR8();
  }
#undef STAGE8
#undef RDA8
#undef RDB8
#undef MM8
#undef BAR8
#undef LGKM0
}

// ---------------- fused QKV GEMM (C^T) + RMSNorm + RoPE + head scatter ----------------
// 256x256 tiles: blockIdx.x -> 256 qkv-dims (2 heads), blockIdx.y -> 256 tokens.
// A-operand = Wcat rows (d), B-operand = xb rows (tokens). Each m-wave owns one FULL
// head (128 d) -> RMS reduction is entirely in-wave (2 shfl_xor, no LDS pass).
__global__ __launch_bounds__(512) void gemm_qkv_fused(const u16* __restrict__ xb,
                                                      const u16* __restrict__ Wcat,
                                                      const float* __restrict__ freqs,
                                                      u16* __restrict__ qb, u16* __restrict__ kb,
                                                      u16* __restrict__ vb) {
  extern __shared__ char smem[];
  const int n0d = blockIdx.x * 256;   // qkv-dim offset (Q:<2048, K:2048..2560, V:>=2560)
  const int t0 = blockIdx.y * 256;    // token offset
  f32x4 acc[8][4] = {};
  core8(Wcat, xb, n0d, t0, smem, acc);

  const int tid = threadIdx.x;
  const int lane = tid & 63, w = tid >> 6;
  const int wm = w >> 2, wn = w & 3;
  const int quad = lane >> 4, lo = lane & 15;
  const int bb = t0 >> 11;            // batch (256-token tile never crosses batches)

  if (n0d >= 2560) {                  // ---- V: direct transposed store (vb = B*HKV, D, T) ----
    int head = ((n0d - 2560) >> 7) + wm;
    size_t vbase = (size_t)(bb * HKV_ + head) * D_ * T_;
#pragma unroll
    for (int n = 0; n < 4; n++) {
      int t = (t0 & 2047) + wn * 64 + n * 16 + lo;
#pragma unroll
      for (int m = 0; m < 8; m++) {
        int dd = m * 16 + quad * 4;
#pragma unroll
        for (int r = 0; r < 4; r++)
          vb[vbase + (size_t)(dd + r) * T_ + t] = f2bf(acc[m][n][r]);
      }
    }
    return;
  }

  // ---- Q/K: RMSNorm (in-wave: lane covers 32 of its head's 128 d, reduce over quads) ----
  const int isQ = (n0d < 2048) ? 1 : 0;
  const float qs = isQ ? 0.08838834764831845f : 1.0f;   // 1/sqrt(D) folded into q
  float ss[4] = {0.f, 0.f, 0.f, 0.f};
#pragma unroll
  for (int m = 0; m < 8; m++)
#pragma unroll
    for (int n = 0; n < 4; n++)
#pragma unroll
      for (int r = 0; r < 4; r++) ss[n] += acc[m][n][r] * acc[m][n][r];
#pragma unroll
  for (int n = 0; n < 4; n++) {
    ss[n] += __shfl_xor(ss[n], 16, 64);
    ss[n] += __shfl_xor(ss[n], 32, 64);
    ss[n] = rsqrtf(ss[n] * (1.0f / 128.0f) + 1e-6f) * qs;  // reuse as scale
  }

  // ---- RoPE + LDS transpose + store, one head (m-wave) at a time ----
  u16* Tr = (u16*)smem;               // [256 tokens][136 d-stride] u16
  const int baseh = isQ ? (n0d >> 7) : ((n0d - 2048) >> 7);
  const int heads = isQ ? H_ : HKV_;
  u16* dst = isQ ? qb : kb;
#pragma unroll
  for (int hh = 0; hh < 2; hh++) {
    if (wm == hh) {
#pragma unroll
      for (int n = 0; n < 4; n++) {
        int tl = wn * 64 + n * 16 + lo;
        const float* fp = freqs + (size_t)((t0 & 2047) + tl) * 128;
#pragma unroll
        for (int m = 0; m < 8; m++) {
          float4 f = *(const float4*)(fp + m * 16 + quad * 4);
          float a0 = acc[m][n][0] * ss[n], a1 = acc[m][n][1] * ss[n];
          unsigned pk0 = (unsigned)f2bf(a0 * f.x - a1 * f.y) |
                         (((unsigned)f2bf(a0 * f.y + a1 * f.x)) << 16);
          float a2 = acc[m][n][2] * ss[n], a3 = acc[m][n][3] * ss[n];
          unsigned pk1 = (unsigned)f2bf(a2 * f.z - a3 * f.w) |
                         (((unsigned)f2bf(a2 * f.w + a3 * f.z)) << 16);
          int dd = m * 16 + quad * 4;
          *(unsigned*)(&Tr[tl * 136 + dd]) = pk0;
          *(unsigned*)(&Tr[tl * 136 + dd + 2]) = pk1;
        }
      }
    }
    __syncthreads();
    int head = baseh + hh;
    int ic = tid & 15, r0 = tid >> 4;
#pragma unroll
    for (int j = 0; j < 8; j++) {
      int tl = r0 + j * 32;
      int g = t0 + tl;
      int b = g >> 11, tt = g & 2047;
      uint4 v4 = *(const uint4*)(&Tr[tl * 136 + ic * 8]);
      *(uint4*)(&dst[((size_t)(b * heads + head) * T_ + tt) * D_ + ic * 8]) = v4;
    }
    __syncthreads();
  }
}

// ---------------- final projection: out(8192,2048) = yb(8192,2048) * WcT(2048,2048)^T ----------------
__global__ __launch_bounds__(512) void gemm_wc(const u16* __restrict__ yb,
                                               const u16* __restrict__ WcT,
                                               float* __restrict__ out) {
  extern __shared__ char smem[];
  const int n0 = blockIdx.x * 256, m0 = blockIdx.y * 256;
  f32x4 acc[8][4] = {};
  core8(yb, WcT, m0, n0, smem, acc);

  const int tid = threadIdx.x;
  const int lane = tid & 63, w = tid >> 6;
  const int wm = w >> 2, wn = w & 3;
  const int quad = lane >> 4, lo = lane & 15;
#pragma unroll
  for (int m = 0; m < 8; m++)
#pragma unroll
    for (int n = 0; n < 4; n++)
#pragma unroll
      for (int r = 0; r < 4; r++) {
        int mg = m0 + wm * 128 + m * 16 + quad * 4 + r;
        int ng = n0 + wn * 64 + n * 16 + lo;
        out[(size_t)mg * 2048 + ng] = acc[m][n][r];
      }
}

// ---------------- Flash attention, causal, GQA, triangle-paired (unchanged) ----------------
__global__ __launch_bounds__(256) void flash_kernel(const u16* __restrict__ qb, const u16* __restrict__ kb,
                                                    const u16* __restrict__ vb, u16* __restrict__ yb) {
  __shared__ __align__(16) u16 smem[17408];
  u16* Ks = smem;              // 64 keys x 128 d, 16B chunks XOR-swizzled: chunk' = c ^ (row&7)
  u16* Vs = smem + 8192;       // 128 d x 64 keys, chunk' = c ^ (row&7)
  int bh = blockIdx.x;
  int b = bh >> 4, hq = bh & 15;
  int jp = blockIdx.y;
  int tid = threadIdx.x, w = tid >> 6, lane = tid & 63;
  int half = lane >> 5, lq = lane & 31;
  int bhkv = b * HKV_ + (hq >> 2);
  const u16* kbase = kb + (size_t)bhkv * T_ * D_;
  const u16* vbase = vb + (size_t)bhkv * D_ * T_;
  const float L2E = 1.4426950408889634f;
  const float N12 = -17.312340490667562f;

  int kchunk = lane & 15, krow0 = w * 16 + (lane >> 4);
  int vchunk = lane & 7, vrow0 = w * 32 + (lane >> 3);

  for (int ph = 0; ph < 2; ph++) {
    int qt = ph ? jp : (15 - jp);
    const u16* qbase = qb + ((size_t)bh * T_ + qt * 128) * D_;
    int qwave = qt * 128 + w * 32;

    bf16x8 qf[8];
#pragma unroll
    for (int ds = 0; ds < 8; ds++)
      qf[ds] = *(const bf16x8*)(&qbase[(w * 32 + lq) * D_ + ds * 16 + half * 8]);

    f32x16 oacc[4] = {};
    float l_part = 0.f;

    int ktmax = 2 * qt + 1;
    for (int kt = 0; kt <= ktmax; kt++) {
      const u16* ksrc = kbase + (size_t)(kt * 64) * D_;
      const u16* vsrc = vbase + kt * 64;
#pragma unroll
      for (int c = 0; c < 4; c++) {
        int r = krow0 + c * 4;
        async_cp16(&ksrc[r * D_ + ((kchunk ^ (r & 7)) << 3)], &Ks[r * 128 + (kchunk << 3)]);
      }
#pragma unroll
      for (int c = 0; c < 4; c++) {
        int r = vrow0 + c * 8;
        async_cp16(&vsrc[(size_t)r * T_ + ((vchunk ^ (r & 7)) << 3)], &Vs[r * 64 + (vchunk << 3)]);
      }
      __syncthreads();

#pragma unroll
      for (int t = 0; t < 2; t++) {
        int k0 = kt * 64 + t * 32;
        if (k0 > qwave + 31) continue;

        f32x16 s = {};
#pragma unroll
        for (int ds = 0; ds < 8; ds++) {
          bf16x8 kf = *(const bf16x8*)(&Ks[(t * 32 + lq) * 128 + ((((ds << 1) + half) ^ (lq & 7)) << 3)]);
          s = __builtin_amdgcn_mfma_f32_32x32x16_bf16(kf, qf[ds], s, 0, 0, 0);
        }

        int qglob = qwave + lq;
        if (k0 + 31 > qwave) {
#pragma unroll
          for (int i = 0; i < 16; i++) {
            int kl = k0 + 4 * half + (i & 3) + ((i >> 2) << 3);
            if (kl > qglob) s[i] = -1e30f;
          }
        }

        unsigned pd[8];
#pragma unroll
        for (int j2 = 0; j2 < 8; j2++) {
          float p0 = __builtin_amdgcn_exp2f(fmaf(s[2 * j2], L2E, N12));
          float p1 = __builtin_amdgcn_exp2f(fmaf(s[2 * j2 + 1], L2E, N12));
          l_part += p0 + p1;
          pd[j2] = __builtin_amdgcn_perm(__builtin_bit_cast(unsigned, p1),
                                         __builtin_bit_cast(unsigned, p0), 0x07060302u);
        }

        unsigned s0 = (unsigned)__shfl_xor((int)(half ? pd[0] : pd[2]), 32, 64);
        unsigned s1 = (unsigned)__shfl_xor((int)(half ? pd[1] : pd[3]), 32, 64);
        unsigned s2 = (unsigned)__shfl_xor((int)(half ? pd[4] : pd[6]), 32, 64);
        unsigned s3 = (unsigned)__shfl_xor((int)(half ? pd[5] : pd[7]), 32, 64);
        uint4 f0 = half ? uint4{s0, s1, pd[2], pd[3]} : uint4{pd[0], pd[1], s0, s1};
        uint4 f1 = half ? uint4{s2, s3, pd[6], pd[7]} : uint4{pd[4], pd[5], s2, s3};

#pragma unroll
        for (int kstep = 0; kstep < 2; kstep++) {
          uint4 fr = kstep ? f1 : f0;
          bf16x8 pf = __builtin_bit_cast(bf16x8, fr);
          int cR = (t * 2 + kstep) * 2 + half;
#pragma unroll
          for (int dt = 0; dt < 4; dt++) {
            bf16x8 vf = *(const bf16x8*)(&Vs[(dt * 32 + lq) * 64 + ((cR ^ (lq & 7)) << 3)]);
            oacc[dt] = __builtin_amdgcn_mfma_f32_32x32x16_bf16(vf, pf, oacc[dt], 0, 0, 0);
          }
        }
      }
      __syncthreads();
    }

    float lt = l_part + __shfl_xor(l_part, 32, 64);
    float inv = 1.0f / lt;

    u16* Ep = smem;
#pragma unroll
    for (int dt = 0; dt < 4; dt++)
#pragma unroll
      for (int j2 = 0; j2 < 8; j2++) {
        float p0 = oacc[dt][2 * j2] * inv;
        float p1 = oacc[dt][2 * j2 + 1] * inv;
        unsigned pk = ((unsigned)f2bf(p0)) | (((unsigned)f2bf(p1)) << 16);
        int d = dt * 32 + 4 * half + 2 * (j2 & 1) + ((j2 >> 1) << 3);
        *(unsigned*)(&Ep[(w * 32 + lq) * 136 + d]) = pk;
      }
    __syncthreads();

    int ic = tid & 15, qr0 = tid >> 4;
    size_t orow = ((size_t)b * T_ + qt * 128) * 2048 + hq * 128;
#pragma unroll
    for (int j2 = 0; j2 < 8; j2++) {
      int qr = qr0 + j2 * 16;
      uint4 v4 = *(const uint4*)(&Ep[qr * 136 + ic * 8]);
      *(uint4*)(&yb[orow + (size_t)qr * 2048 + ic * 8]) = v4;
    }
    __syncthreads();
  }
}

extern "C" void kernel_launch(void* const* d_in, const int* in_sizes, int n_in,
                              void* d_out, int out_size, void* d_ws, size_t ws_size,
                              hipStream_t stream) {
  const float* x = (const float*)d_in[0];
  const float* freqs = (const float*)d_in[1];
  const float* Wq = (const float*)d_in[2];
  const float* Wk = (const float*)d_in[3];
  const float* Wv = (const float*)d_in[4];
  const float* Wc = (const float*)d_in[5];
  float* out = (float*)d_out;

  char* ws = (char*)d_ws;
  size_t off = 0;
  auto alloc = [&](size_t bytes) { char* p = ws + off; off += (bytes + 255) & ~255ull; return p; };
  u16* xb   = (u16*)alloc((size_t)B_ * T_ * C_ * 2);
  u16* Wcat = (u16*)alloc((size_t)C_ * 3072 * 2);
  u16* WcT  = (u16*)alloc((size_t)C_ * C_ * 2);
  u16* qb   = (u16*)alloc((size_t)B_ * H_ * T_ * D_ * 2);
  u16* kb   = (u16*)alloc((size_t)B_ * HKV_ * T_ * D_ * 2);
  u16* vb   = (u16*)alloc((size_t)B_ * HKV_ * T_ * D_ * 2);
  u16* yb   = (u16*)alloc((size_t)B_ * T_ * H_ * D_ * 2);

  static bool attr_done = false;
  if (!attr_done) {
    (void)hipFuncSetAttribute(reinterpret_cast<const void*>(gemm_qkv_fused),
                              hipFuncAttributeMaxDynamicSharedMemorySize, 131072);
    (void)hipFuncSetAttribute(reinterpret_cast<const void*>(gemm_wc),
                              hipFuncAttributeMaxDynamicSharedMemorySize, 131072);
    attr_done = true;
  }

  prep_kernel<<<dim3(4096 + 2560), dim3(256), 0, stream>>>(x, Wq, Wk, Wv, Wc, xb, Wcat, WcT);
  gemm_qkv_fused<<<dim3(12, 32), dim3(512), 131072, stream>>>(xb, Wcat, freqs, qb, kb, vb);
  flash_kernel<<<dim3(B_ * H_, 8), dim3(256), 0, stream>>>(qb, kb, vb, yb);
  gemm_wc<<<dim3(8, 32), dim3(512), 131072, stream>>>(yb, WcT, out);
}

// Round 2
// 428.156 us; speedup vs baseline: 1.0424x; 1.0227x over previous
//
#include <hip/hip_runtime.h>
#include <cstdint>

#define B_ 4
#define T_ 2048
#define C_ 2048
#define H_ 16
#define HKV_ 4
#define D_ 128

typedef unsigned short u16;
typedef __bf16 bf16x8 __attribute__((ext_vector_type(8)));
typedef float f32x4 __attribute__((ext_vector_type(4)));
typedef float f32x16 __attribute__((ext_vector_type(16)));

typedef __attribute__((address_space(1))) const void gvoid;
typedef __attribute__((address_space(3))) void lvoid;

static __device__ __forceinline__ void async_cp16(const u16* g, u16* l) {
  __builtin_amdgcn_global_load_lds((gvoid*)g, (lvoid*)l, 16, 0, 0);
}

static __device__ __forceinline__ u16 f2bf(float f) {
  unsigned int x = __builtin_bit_cast(unsigned int, f);
  x += 0x7fffu + ((x >> 16) & 1u);
  return (u16)(x >> 16);
}

// ---------------- prep: cast x fp32->bf16 (blocks 0..4095) + weight transposes ----------------
__global__ void prep_kernel(const float* __restrict__ x, const float* __restrict__ Wq,
                            const float* __restrict__ Wk, const float* __restrict__ Wv,
                            const float* __restrict__ Wc, u16* __restrict__ xb,
                            u16* __restrict__ Wcat, u16* __restrict__ WcT) {
  __shared__ float tile[64][65];
  int tb = blockIdx.x, tid = threadIdx.x;
  if (tb < 4096) {                       // cast: 4096 blocks x 1024 float4
    const float4* in4 = (const float4*)x;
#pragma unroll
    for (int j = 0; j < 4; j++) {
      int i = tb * 1024 + j * 256 + tid;
      float4 v = in4[i];
      ushort4 o;
      o.x = f2bf(v.x); o.y = f2bf(v.y); o.z = f2bf(v.z); o.w = f2bf(v.w);
      ((ushort4*)xb)[i] = o;
    }
    return;
  }
  int tb2 = tb - 4096;
  const float* W; u16* WT; int Nw, t;
  if (tb2 < 1024)      { W = Wq; WT = Wcat;                       Nw = 2048; t = tb2; }
  else if (tb2 < 1280) { W = Wk; WT = Wcat + (size_t)2048 * 2048; Nw = 512;  t = tb2 - 1024; }
  else if (tb2 < 1536) { W = Wv; WT = Wcat + (size_t)2560 * 2048; Nw = 512;  t = tb2 - 1280; }
  else                 { W = Wc; WT = WcT;                        Nw = 2048; t = tb2 - 1536; }
  int ntiles = Nw >> 6;
  int n0 = (t % ntiles) * 64, k0 = (t / ntiles) * 64;
#pragma unroll
  for (int i = 0; i < 16; i++) {
    int idx = i * 256 + tid;
    int r = idx >> 6, c = idx & 63;
    tile[r][c] = W[(size_t)(k0 + r) * Nw + n0 + c];
  }
  __syncthreads();
#pragma unroll
  for (int i = 0; i < 16; i++) {
    int idx = i * 256 + tid;
    int r = idx >> 6, c = idx & 63;
    WT[(size_t)(n0 + r) * 2048 + k0 + c] = f2bf(tile[c][r]);
  }
}

// ================= 8-phase 256x256 GEMM core (T2+T3+T4+T5, plain HIP) =================
// Stage order per tile t (deepened B prefetch vs r1):
//   ph0: B-lo(t+1) + B-hi(t+1)   ph2: A-lo(t+2)   ph3: A-hi(t+2)
// Safety: B(t+1) region (parity (t+1)&1) last read by tile t-1 at its ph0-2 (done by
// t-1 ph2 end-barrier); A(t+2) region (parity t&1) last read at t ph0-1. Every stage
// issue is >=1 barrier-pair after the last read. vmcnt(4) at ph3 waits A(t+1)+B(t+1)
// (8 oldest of 12 in flight), leaves A(t+2) flying. vmcnt(0) only at t==30.
static __device__ __forceinline__ void core8(const u16* __restrict__ Aop,
                                             const u16* __restrict__ Bop,
                                             int m0, int n0, char* smem,
                                             f32x4 (&acc)[8][4]) {
  const int tid = threadIdx.x;
  const int lane = tid & 63, w = tid >> 6;
  const int wm = w >> 2, wn = w & 3;
  const int quad = lane >> 4, lo = lane & 15;
  const int sr = tid >> 3, sc = tid & 7;
  const int gcol = (sc ^ (sr & 7)) << 3;
  const u16* sA = Aop + (size_t)(m0 + sr) * 2048 + gcol;
  const u16* sB = Bop + (size_t)(n0 + sr) * 2048 + gcol;
  const int c0 = ((quad ^ (lo & 7)) << 4);
  const int c1 = (((4 + quad) ^ (lo & 7)) << 4);
  char* rA = smem + (wm * 128 + lo) * 128;
  char* rB = smem + 32768 + (wn * 64 + lo) * 128;
  bf16x8 Af[8][2], Bf[2][2];

#define STAGE8(u, j)                                                                         \
  do {                                                                                       \
    if ((u) < 32) {                                                                          \
      const u16* s_ = (((j) & 2) ? sB : sA) + (((j) & 1) ? (size_t)262144 : (size_t)0) +     \
                      (size_t)(u) * 64;                                                      \
      char* d_ = smem + (((u) & 1) << 16) + (((j) & 2) << 14) + (((j) & 1) << 14) + tid * 16;\
      async_cp16(s_, (u16*)d_);                                                              \
      async_cp16(s_ + 131072, (u16*)(d_ + 8192));                                            \
    }                                                                                        \
  } while (0)

#define RDA8(boff, mlo)                                                                      \
  do {                                                                                       \
    _Pragma("unroll") for (int m_ = 0; m_ < 4; m_++) {                                       \
      char* p_ = rA + (boff) + ((mlo) + m_) * 2048;                                          \
      Af[(mlo) + m_][0] = *(const bf16x8*)(p_ + c0);                                         \
      Af[(mlo) + m_][1] = *(const bf16x8*)(p_ + c1);                                         \
    }                                                                                        \
  } while (0)

#define RDB8(boff, nlo)                                                                      \
  do {                                                                                       \
    _Pragma("unroll") for (int n_ = 0; n_ < 2; n_++) {                                       \
      char* p_ = rB + (boff) + ((nlo) + n_) * 2048;                                          \
      Bf[n_][0] = *(const bf16x8*)(p_ + c0);                                                 \
      Bf[n_][1] = *(const bf16x8*)(p_ + c1);                                                 \
    }                                                                                        \
  } while (0)

#define MM8(mlo, nlo)                                                                        \
  do {                                                                                       \
    __builtin_amdgcn_s_setprio(1);                                                           \
    _Pragma("unroll") for (int m_ = 0; m_ < 4; m_++)                                         \
      _Pragma("unroll") for (int n_ = 0; n_ < 2; n_++)                                       \
        _Pragma("unroll") for (int k_ = 0; k_ < 2; k_++)                                     \
          acc[(mlo) + m_][(nlo) + n_] = __builtin_amdgcn_mfma_f32_16x16x32_bf16(             \
              Af[(mlo) + m_][k_], Bf[n_][k_], acc[(mlo) + m_][(nlo) + n_], 0, 0, 0);         \
    __builtin_amdgcn_s_setprio(0);                                                           \
  } while (0)

#define BAR8() __builtin_amdgcn_s_barrier()
#define LGKM0() asm volatile("s_waitcnt lgkmcnt(0)" ::: "memory")

  // prologue: A(0), B(0), A(1); wait A0+B0 (oldest 8 of 12)
  STAGE8(0, 0); STAGE8(0, 1); STAGE8(0, 2); STAGE8(0, 3);
  STAGE8(1, 0); STAGE8(1, 1);
  asm volatile("s_waitcnt vmcnt(4)" ::: "memory");
  BAR8();

#pragma unroll 1
  for (int t = 0; t < 32; t++) {
    const int boff = (t & 1) << 16;
    // phase 0: quadrant (m0-3, n0-1); stage both B(t+1) halves
    RDA8(boff, 0); RDB8(boff, 0);
    STAGE8(t + 1, 2); STAGE8(t + 1, 3);
    BAR8(); LGKM0();
    MM8(0, 0);
    BAR8();
    // phase 1: quadrant (m4-7, n0-1)
    RDA8(boff, 4);
    BAR8(); LGKM0();
    MM8(4, 0);
    BAR8();
    // phase 2: quadrant (m4-7, n2-3); stage A-lo(t+2)
    RDB8(boff, 2);
    STAGE8(t + 2, 0);
    BAR8(); LGKM0();
    MM8(4, 2);
    BAR8();
    // phase 3: quadrant (m0-3, n2-3); stage A-hi(t+2); counted vmcnt once per tile
    STAGE8(t + 2, 1);
    if (t < 30) {
      asm volatile("s_waitcnt vmcnt(4)" ::: "memory");
    } else if (t == 30) {
      asm volatile("s_waitcnt vmcnt(0)" ::: "memory");
    }
    BAR8(); LGKM0();
    MM8(0, 2);
    BAR8();
  }
#undef STAGE8
#undef RDA8
#undef RDB8
#undef MM8
#undef BAR8
#undef LGKM0
}

// ---------------- fused QKV GEMM (C^T) + RMSNorm + RoPE + head scatter ----------------
__global__ __launch_bounds__(512) void gemm_qkv_fused(const u16* __restrict__ xb,
                                                      const u16* __restrict__ Wcat,
                                                      const float* __restrict__ freqs,
                                                      u16* __restrict__ qb, u16* __restrict__ kb,
                                                      u16* __restrict__ vb) {
  extern __shared__ char smem[];
  // T1 bijective XCD swizzle: nwg=384, cpx=48 -> each XCD gets 4 contiguous token-tiles
  // (4 MB xb panels L2-resident) x all 12 dim-tiles.
  int bid = blockIdx.y * 12 + blockIdx.x;
  int swz = (bid & 7) * 48 + (bid >> 3);
  const int n0d = (swz % 12) * 256;   // qkv-dim offset (Q:<2048, K:2048..2560, V:>=2560)
  const int t0 = (swz / 12) * 256;    // token offset
  f32x4 acc[8][4] = {};
  core8(Wcat, xb, n0d, t0, smem, acc);

  const int tid = threadIdx.x;
  const int lane = tid & 63, w = tid >> 6;
  const int wm = w >> 2, wn = w & 3;
  const int quad = lane >> 4, lo = lane & 15;
  const int bb = t0 >> 11;            // batch (256-token tile never crosses batches)

  if (n0d >= 2560) {                  // ---- V: direct transposed store (vb = B*HKV, D, T) ----
    int head = ((n0d - 2560) >> 7) + wm;
    size_t vbase = (size_t)(bb * HKV_ + head) * D_ * T_;
#pragma unroll
    for (int n = 0; n < 4; n++) {
      int t = (t0 & 2047) + wn * 64 + n * 16 + lo;
#pragma unroll
      for (int m = 0; m < 8; m++) {
        int dd = m * 16 + quad * 4;
#pragma unroll
        for (int r = 0; r < 4; r++)
          vb[vbase + (size_t)(dd + r) * T_ + t] = f2bf(acc[m][n][r]);
      }
    }
    return;
  }

  // ---- Q/K: RMSNorm (in-wave: lane covers 32 of its head's 128 d, reduce over quads) ----
  const int isQ = (n0d < 2048) ? 1 : 0;
  const float qs = isQ ? 0.08838834764831845f : 1.0f;   // 1/sqrt(D) folded into q
  float ss[4] = {0.f, 0.f, 0.f, 0.f};
#pragma unroll
  for (int m = 0; m < 8; m++)
#pragma unroll
    for (int n = 0; n < 4; n++)
#pragma unroll
      for (int r = 0; r < 4; r++) ss[n] += acc[m][n][r] * acc[m][n][r];
#pragma unroll
  for (int n = 0; n < 4; n++) {
    ss[n] += __shfl_xor(ss[n], 16, 64);
    ss[n] += __shfl_xor(ss[n], 32, 64);
    ss[n] = rsqrtf(ss[n] * (1.0f / 128.0f) + 1e-6f) * qs;  // reuse as scale
  }

  // ---- RoPE + LDS transpose + store, one head (m-wave) at a time ----
  u16* Tr = (u16*)smem;               // [256 tokens][136 d-stride] u16
  const int baseh = isQ ? (n0d >> 7) : ((n0d - 2048) >> 7);
  const int heads = isQ ? H_ : HKV_;
  u16* dst = isQ ? qb : kb;
#pragma unroll
  for (int hh = 0; hh < 2; hh++) {
    if (wm == hh) {
#pragma unroll
      for (int n = 0; n < 4; n++) {
        int tl = wn * 64 + n * 16 + lo;
        const float* fp = freqs + (size_t)((t0 & 2047) + tl) * 128;
#pragma unroll
        for (int m = 0; m < 8; m++) {
          float4 f = *(const float4*)(fp + m * 16 + quad * 4);
          float a0 = acc[m][n][0] * ss[n], a1 = acc[m][n][1] * ss[n];
          unsigned pk0 = (unsigned)f2bf(a0 * f.x - a1 * f.y) |
                         (((unsigned)f2bf(a0 * f.y + a1 * f.x)) << 16);
          float a2 = acc[m][n][2] * ss[n], a3 = acc[m][n][3] * ss[n];
          unsigned pk1 = (unsigned)f2bf(a2 * f.z - a3 * f.w) |
                         (((unsigned)f2bf(a2 * f.w + a3 * f.z)) << 16);
          int dd = m * 16 + quad * 4;
          *(unsigned*)(&Tr[tl * 136 + dd]) = pk0;
          *(unsigned*)(&Tr[tl * 136 + dd + 2]) = pk1;
        }
      }
    }
    __syncthreads();
    int head = baseh + hh;
    int ic = tid & 15, r0 = tid >> 4;
#pragma unroll
    for (int j = 0; j < 8; j++) {
      int tl = r0 + j * 32;
      int g = t0 + tl;
      int b = g >> 11, tt = g & 2047;
      uint4 v4 = *(const uint4*)(&Tr[tl * 136 + ic * 8]);
      *(uint4*)(&dst[((size_t)(b * heads + head) * T_ + tt) * D_ + ic * 8]) = v4;
    }
    __syncthreads();
  }
}

// ---------------- final projection: out(8192,2048) = yb(8192,2048) * WcT(2048,2048)^T ----------------
__global__ __launch_bounds__(512) void gemm_wc(const u16* __restrict__ yb,
                                               const u16* __restrict__ WcT,
                                               float* __restrict__ out) {
  extern __shared__ char smem[];
  // T1 swizzle: nwg=256, cpx=32 -> each XCD: 4 yb m-panels + all 8 WcT panels (12 MB vs 33 MB)
  int bid = blockIdx.y * 8 + blockIdx.x;
  int swz = (bid & 7) * 32 + (bid >> 3);
  const int n0 = (swz & 7) * 256, m0 = (swz >> 3) * 256;
  f32x4 acc[8][4] = {};
  core8(yb, WcT, m0, n0, smem, acc);

  const int tid = threadIdx.x;
  const int lane = tid & 63, w = tid >> 6;
  const int wm = w >> 2, wn = w & 3;
  const int quad = lane >> 4, lo = lane & 15;
#pragma unroll
  for (int m = 0; m < 8; m++)
#pragma unroll
    for (int n = 0; n < 4; n++)
#pragma unroll
      for (int r = 0; r < 4; r++) {
        int mg = m0 + wm * 128 + m * 16 + quad * 4 + r;
        int ng = n0 + wn * 64 + n * 16 + lo;
        out[(size_t)mg * 2048 + ng] = acc[m][n][r];
      }
}

// ---------------- Flash attention, causal, GQA, triangle-paired ----------------
// r2: double-buffered K/V staging with counted vmcnt(8) + raw barriers (T3/T4 minimal),
// dual independent QK MFMA chains, setprio around MFMA clusters (T5).
__global__ __launch_bounds__(256) void flash_kernel(const u16* __restrict__ qb, const u16* __restrict__ kb,
                                                    const u16* __restrict__ vb, u16* __restrict__ yb) {
  __shared__ __align__(16) u16 smem[32768];   // 2x Ks(64x128) + 2x Vs(128x64) = 64 KB
  int bh = blockIdx.x;
  int b = bh >> 4, hq = bh & 15;
  int jp = blockIdx.y;
  int tid = threadIdx.x, w = tid >> 6, lane = tid & 63;
  int half = lane >> 5, lq = lane & 31;
  int bhkv = b * HKV_ + (hq >> 2);
  const u16* kbase = kb + (size_t)bhkv * T_ * D_;
  const u16* vbase = vb + (size_t)bhkv * D_ * T_;
  const float L2E = 1.4426950408889634f;
  const float N12 = -17.312340490667562f;

  int kchunk = lane & 15, krow0 = w * 16 + (lane >> 4);
  int vchunk = lane & 7, vrow0 = w * 32 + (lane >> 3);

  for (int ph = 0; ph < 2; ph++) {
    int qt = ph ? jp : (15 - jp);
    const u16* qbase = qb + ((size_t)bh * T_ + qt * 128) * D_;
    int qwave = qt * 128 + w * 32;

    bf16x8 qf[8];
#pragma unroll
    for (int ds = 0; ds < 8; ds++)
      qf[ds] = *(const bf16x8*)(&qbase[(w * 32 + lq) * D_ + ds * 16 + half * 8]);

    f32x16 oacc[4] = {};
    float l_part = 0.f;

    int ktmax = 2 * qt + 1;

#define STAGEF(kt_)                                                                          \
    do {                                                                                     \
      const u16* ks_ = kbase + (size_t)((kt_) * 64) * D_;                                    \
      const u16* vs_ = vbase + (kt_) * 64;                                                   \
      u16* K_ = smem + (((kt_) & 1) << 13);                                                  \
      u16* V_ = smem + 16384 + (((kt_) & 1) << 13);                                          \
      _Pragma("unroll") for (int c_ = 0; c_ < 4; c_++) {                                     \
        int r_ = krow0 + c_ * 4;                                                             \
        async_cp16(&ks_[r_ * D_ + ((kchunk ^ (r_ & 7)) << 3)], &K_[r_ * 128 + (kchunk << 3)]);\
      }                                                                                      \
      _Pragma("unroll") for (int c_ = 0; c_ < 4; c_++) {                                     \
        int r_ = vrow0 + c_ * 8;                                                             \
        async_cp16(&vs_[(size_t)r_ * T_ + ((vchunk ^ (r_ & 7)) << 3)], &V_[r_ * 64 + (vchunk << 3)]);\
      }                                                                                      \
    } while (0)

    STAGEF(0);
    for (int kt = 0; kt <= ktmax; kt++) {
      if (kt < ktmax) {
        STAGEF(kt + 1);
        asm volatile("s_waitcnt vmcnt(8)" ::: "memory");   // wait buf[kt]'s 8 loads
      } else {
        asm volatile("s_waitcnt vmcnt(0)" ::: "memory");
      }
      __builtin_amdgcn_s_barrier();
      const u16* Ks = smem + ((kt & 1) << 13);
      const u16* Vs = smem + 16384 + ((kt & 1) << 13);

#pragma unroll
      for (int t = 0; t < 2; t++) {
        int k0 = kt * 64 + t * 32;
        if (k0 > qwave + 31) continue;

        f32x16 s = {}, sb = {};
        __builtin_amdgcn_s_setprio(1);
#pragma unroll
        for (int ds = 0; ds < 4; ds++) {
          bf16x8 kf = *(const bf16x8*)(&Ks[(t * 32 + lq) * 128 + ((((ds << 1) + half) ^ (lq & 7)) << 3)]);
          s = __builtin_amdgcn_mfma_f32_32x32x16_bf16(kf, qf[ds], s, 0, 0, 0);
        }
#pragma unroll
        for (int ds = 4; ds < 8; ds++) {
          bf16x8 kf = *(const bf16x8*)(&Ks[(t * 32 + lq) * 128 + ((((ds << 1) + half) ^ (lq & 7)) << 3)]);
          sb = __builtin_amdgcn_mfma_f32_32x32x16_bf16(kf, qf[ds], sb, 0, 0, 0);
        }
        __builtin_amdgcn_s_setprio(0);
        s = s + sb;

        int qglob = qwave + lq;
        if (k0 + 31 > qwave) {
#pragma unroll
          for (int i = 0; i < 16; i++) {
            int kl = k0 + 4 * half + (i & 3) + ((i >> 2) << 3);
            if (kl > qglob) s[i] = -1e30f;
          }
        }

        unsigned pd[8];
#pragma unroll
        for (int j2 = 0; j2 < 8; j2++) {
          float p0 = __builtin_amdgcn_exp2f(fmaf(s[2 * j2], L2E, N12));
          float p1 = __builtin_amdgcn_exp2f(fmaf(s[2 * j2 + 1], L2E, N12));
          l_part += p0 + p1;
          pd[j2] = __builtin_amdgcn_perm(__builtin_bit_cast(unsigned, p1),
                                         __builtin_bit_cast(unsigned, p0), 0x07060302u);
        }

        unsigned s0 = (unsigned)__shfl_xor((int)(half ? pd[0] : pd[2]), 32, 64);
        unsigned s1 = (unsigned)__shfl_xor((int)(half ? pd[1] : pd[3]), 32, 64);
        unsigned s2 = (unsigned)__shfl_xor((int)(half ? pd[4] : pd[6]), 32, 64);
        unsigned s3 = (unsigned)__shfl_xor((int)(half ? pd[5] : pd[7]), 32, 64);
        uint4 f0 = half ? uint4{s0, s1, pd[2], pd[3]} : uint4{pd[0], pd[1], s0, s1};
        uint4 f1 = half ? uint4{s2, s3, pd[6], pd[7]} : uint4{pd[4], pd[5], s2, s3};

        __builtin_amdgcn_s_setprio(1);
#pragma unroll
        for (int kstep = 0; kstep < 2; kstep++) {
          uint4 fr = kstep ? f1 : f0;
          bf16x8 pf = __builtin_bit_cast(bf16x8, fr);
          int cR = (t * 2 + kstep) * 2 + half;
#pragma unroll
          for (int dt = 0; dt < 4; dt++) {
            bf16x8 vf = *(const bf16x8*)(&Vs[(dt * 32 + lq) * 64 + ((cR ^ (lq & 7)) << 3)]);
            oacc[dt] = __builtin_amdgcn_mfma_f32_32x32x16_bf16(vf, pf, oacc[dt], 0, 0, 0);
          }
        }
        __builtin_amdgcn_s_setprio(0);
      }
      __builtin_amdgcn_s_barrier();
    }
#undef STAGEF

    float lt = l_part + __shfl_xor(l_part, 32, 64);
    float inv = 1.0f / lt;

    u16* Ep = smem;
#pragma unroll
    for (int dt = 0; dt < 4; dt++)
#pragma unroll
      for (int j2 = 0; j2 < 8; j2++) {
        float p0 = oacc[dt][2 * j2] * inv;
        float p1 = oacc[dt][2 * j2 + 1] * inv;
        unsigned pk = ((unsigned)f2bf(p0)) | (((unsigned)f2bf(p1)) << 16);
        int d = dt * 32 + 4 * half + 2 * (j2 & 1) + ((j2 >> 1) << 3);
        *(unsigned*)(&Ep[(w * 32 + lq) * 136 + d]) = pk;
      }
    __syncthreads();

    int ic = tid & 15, qr0 = tid >> 4;
    size_t orow = ((size_t)b * T_ + qt * 128) * 2048 + hq * 128;
#pragma unroll
    for (int j2 = 0; j2 < 8; j2++) {
      int qr = qr0 + j2 * 16;
      uint4 v4 = *(const uint4*)(&Ep[qr * 136 + ic * 8]);
      *(uint4*)(&yb[orow + (size_t)qr * 2048 + ic * 8]) = v4;
    }
    __syncthreads();
  }
}

extern "C" void kernel_launch(void* const* d_in, const int* in_sizes, int n_in,
                              void* d_out, int out_size, void* d_ws, size_t ws_size,
                              hipStream_t stream) {
  const float* x = (const float*)d_in[0];
  const float* freqs = (const float*)d_in[1];
  const float* Wq = (const float*)d_in[2];
  const float* Wk = (const float*)d_in[3];
  const float* Wv = (const float*)d_in[4];
  const float* Wc = (const float*)d_in[5];
  float* out = (float*)d_out;

  char* ws = (char*)d_ws;
  size_t off = 0;
  auto alloc = [&](size_t bytes) { char* p = ws + off; off += (bytes + 255) & ~255ull; return p; };
  u16* xb   = (u16*)alloc((size_t)B_ * T_ * C_ * 2);
  u16* Wcat = (u16*)alloc((size_t)C_ * 3072 * 2);
  u16* WcT  = (u16*)alloc((size_t)C_ * C_ * 2);
  u16* qb   = (u16*)alloc((size_t)B_ * H_ * T_ * D_ * 2);
  u16* kb   = (u16*)alloc((size_t)B_ * HKV_ * T_ * D_ * 2);
  u16* vb   = (u16*)alloc((size_t)B_ * HKV_ * T_ * D_ * 2);
  u16* yb   = (u16*)alloc((size_t)B_ * T_ * H_ * D_ * 2);

  static bool attr_done = false;
  if (!attr_done) {
    (void)hipFuncSetAttribute(reinterpret_cast<const void*>(gemm_qkv_fused),
                              hipFuncAttributeMaxDynamicSharedMemorySize, 131072);
    (void)hipFuncSetAttribute(reinterpret_cast<const void*>(gemm_wc),
                              hipFuncAttributeMaxDynamicSharedMemorySize, 131072);
    attr_done = true;
  }

  prep_kernel<<<dim3(4096 + 2560), dim3(256), 0, stream>>>(x, Wq, Wk, Wv, Wc, xb, Wcat, WcT);
  gemm_qkv_fused<<<dim3(12, 32), dim3(512), 131072, stream>>>(xb, Wcat, freqs, qb, kb, vb);
  flash_kernel<<<dim3(B_ * H_, 8), dim3(256), 0, stream>>>(qb, kb, vb, yb);
  gemm_wc<<<dim3(8, 32), dim3(512), 131072, stream>>>(yb, WcT, out);
}

// Round 3
// 419.703 us; speedup vs baseline: 1.0634x; 1.0201x over previous
//
#include <hip/hip_runtime.h>
#include <cstdint>

#define B_ 4
#define T_ 2048
#define C_ 2048
#define H_ 16
#define HKV_ 4
#define D_ 128

typedef unsigned short u16;
typedef __bf16 bf16x8 __attribute__((ext_vector_type(8)));
typedef float f32x4 __attribute__((ext_vector_type(4)));
typedef float f32x16 __attribute__((ext_vector_type(16)));

typedef __attribute__((address_space(1))) const void gvoid;
typedef __attribute__((address_space(3))) void lvoid;

static __device__ __forceinline__ void async_cp16(const u16* g, u16* l) {
  __builtin_amdgcn_global_load_lds((gvoid*)g, (lvoid*)l, 16, 0, 0);
}

static __device__ __forceinline__ u16 f2bf(float f) {
  unsigned int x = __builtin_bit_cast(unsigned int, f);
  x += 0x7fffu + ((x >> 16) & 1u);
  return (u16)(x >> 16);
}

// ---------------- prep: cast x fp32->bf16 (blocks 0..4095) + weight transposes ----------------
__global__ void prep_kernel(const float* __restrict__ x, const float* __restrict__ Wq,
                            const float* __restrict__ Wk, const float* __restrict__ Wv,
                            const float* __restrict__ Wc, u16* __restrict__ xb,
                            u16* __restrict__ Wcat, u16* __restrict__ WcT) {
  __shared__ float tile[64][65];
  int tb = blockIdx.x, tid = threadIdx.x;
  if (tb < 4096) {                       // cast: 4096 blocks x 1024 float4
    const float4* in4 = (const float4*)x;
#pragma unroll
    for (int j = 0; j < 4; j++) {
      int i = tb * 1024 + j * 256 + tid;
      float4 v = in4[i];
      ushort4 o;
      o.x = f2bf(v.x); o.y = f2bf(v.y); o.z = f2bf(v.z); o.w = f2bf(v.w);
      ((ushort4*)xb)[i] = o;
    }
    return;
  }
  int tb2 = tb - 4096;
  const float* W; u16* WT; int Nw, t;
  if (tb2 < 1024)      { W = Wq; WT = Wcat;                       Nw = 2048; t = tb2; }
  else if (tb2 < 1280) { W = Wk; WT = Wcat + (size_t)2048 * 2048; Nw = 512;  t = tb2 - 1024; }
  else if (tb2 < 1536) { W = Wv; WT = Wcat + (size_t)2560 * 2048; Nw = 512;  t = tb2 - 1280; }
  else                 { W = Wc; WT = WcT;                        Nw = 2048; t = tb2 - 1536; }
  int ntiles = Nw >> 6;
  int n0 = (t % ntiles) * 64, k0 = (t / ntiles) * 64;
#pragma unroll
  for (int i = 0; i < 16; i++) {
    int idx = i * 256 + tid;
    int r = idx >> 6, c = idx & 63;
    tile[r][c] = W[(size_t)(k0 + r) * Nw + n0 + c];
  }
  __syncthreads();
#pragma unroll
  for (int i = 0; i < 16; i++) {
    int idx = i * 256 + tid;
    int r = idx >> 6, c = idx & 63;
    WT[(size_t)(n0 + r) * 2048 + k0 + c] = f2bf(tile[c][r]);
  }
}

// ================= 8-phase 256x256 GEMM core — 1 barrier per phase =================
// Phase p = { ds_reads(p); stage; BAR; lgkmcnt(0); MFMA(p) }  — NO trailing barrier.
// A wave that finishes issuing MFMA(p) immediately issues reads(p+1); read latency
// hides under other waves' MFMA(p) + own pipe drain. Max slip = 1 phase.
// Stage-write safety rule (1-bar): stage at phase p needs region's last ds_read at
// phase <= p-2 (arrival at BAR(p-1) implies that phase's reads completed).
//   B(t+1) lo+hi @ ph0(t): last read t-1/ph2  -> p-2 OK
//   A(t+1)-hi    @ ph0(t): last read t-1/ph1  -> p-3 OK
//   A(t+2)-lo    @ ph3(t): last read t/ph1    -> p-2 OK
// vmcnt: single vmcnt(2) per tile at ph3 (completes A(t+1)lo, B(t+1), A(t+1)hi;
// leaves A(t+2)lo flying); vmcnt(0) at t==30; none at t==31.
static __device__ __forceinline__ void core8(const u16* __restrict__ Aop,
                                             const u16* __restrict__ Bop,
                                             int m0, int n0, char* smem,
                                             f32x4 (&acc)[8][4]) {
  const int tid = threadIdx.x;
  const int lane = tid & 63, w = tid >> 6;
  const int wm = w >> 2, wn = w & 3;
  const int quad = lane >> 4, lo = lane & 15;
  const int sr = tid >> 3, sc = tid & 7;
  const int gcol = (sc ^ (sr & 7)) << 3;
  const u16* sA = Aop + (size_t)(m0 + sr) * 2048 + gcol;
  const u16* sB = Bop + (size_t)(n0 + sr) * 2048 + gcol;
  const int c0 = ((quad ^ (lo & 7)) << 4);
  const int c1 = (((4 + quad) ^ (lo & 7)) << 4);
  char* rA = smem + (wm * 128 + lo) * 128;
  char* rB = smem + 32768 + (wn * 64 + lo) * 128;
  bf16x8 Af[8][2], Bf[2][2];

#define STAGE8(u, j)                                                                         \
  do {                                                                                       \
    if ((u) < 32) {                                                                          \
      const u16* s_ = (((j) & 2) ? sB : sA) + (((j) & 1) ? (size_t)262144 : (size_t)0) +     \
                      (size_t)(u) * 64;                                                      \
      char* d_ = smem + (((u) & 1) << 16) + (((j) & 2) << 14) + (((j) & 1) << 14) + tid * 16;\
      async_cp16(s_, (u16*)d_);                                                              \
      async_cp16(s_ + 131072, (u16*)(d_ + 8192));                                            \
    }                                                                                        \
  } while (0)

#define RDA8(boff, mlo)                                                                      \
  do {                                                                                       \
    _Pragma("unroll") for (int m_ = 0; m_ < 4; m_++) {                                       \
      char* p_ = rA + (boff) + ((mlo) + m_) * 2048;                                          \
      Af[(mlo) + m_][0] = *(const bf16x8*)(p_ + c0);                                         \
      Af[(mlo) + m_][1] = *(const bf16x8*)(p_ + c1);                                         \
    }                                                                                        \
  } while (0)

#define RDB8(boff, nlo)                                                                      \
  do {                                                                                       \
    _Pragma("unroll") for (int n_ = 0; n_ < 2; n_++) {                                       \
      char* p_ = rB + (boff) + ((nlo) + n_) * 2048;                                          \
      Bf[n_][0] = *(const bf16x8*)(p_ + c0);                                                 \
      Bf[n_][1] = *(const bf16x8*)(p_ + c1);                                                 \
    }                                                                                        \
  } while (0)

#define MM8(mlo, nlo)                                                                        \
  do {                                                                                       \
    __builtin_amdgcn_s_setprio(1);                                                           \
    _Pragma("unroll") for (int m_ = 0; m_ < 4; m_++)                                         \
      _Pragma("unroll") for (int n_ = 0; n_ < 2; n_++)                                       \
        _Pragma("unroll") for (int k_ = 0; k_ < 2; k_++)                                     \
          acc[(mlo) + m_][(nlo) + n_] = __builtin_amdgcn_mfma_f32_16x16x32_bf16(             \
              Af[(mlo) + m_][k_], Bf[n_][k_], acc[(mlo) + m_][(nlo) + n_], 0, 0, 0);         \
    __builtin_amdgcn_s_setprio(0);                                                           \
  } while (0)

#define BAR8() __builtin_amdgcn_s_barrier()
#define LGKM0() asm volatile("s_waitcnt lgkmcnt(0)" ::: "memory")

  // prologue: A(0) lo+hi, B(0) lo+hi, A(1)-lo; wait tile0 (leaves A(1)-lo flying)
  STAGE8(0, 0); STAGE8(0, 1); STAGE8(0, 2); STAGE8(0, 3);
  STAGE8(1, 0);
  asm volatile("s_waitcnt vmcnt(2)" ::: "memory");
  BAR8();

#pragma unroll 1
  for (int t = 0; t < 32; t++) {
    const int boff = (t & 1) << 16;
    // phase 0: quadrant (m0-3, n0-1); stage B(t+1) lo+hi, A(t+1)-hi
    RDA8(boff, 0); RDB8(boff, 0);
    STAGE8(t + 1, 2); STAGE8(t + 1, 3);
    STAGE8(t + 1, 1);
    BAR8(); LGKM0();
    MM8(0, 0);
    // phase 1: quadrant (m4-7, n0-1)
    RDA8(boff, 4);
    BAR8(); LGKM0();
    MM8(4, 0);
    // phase 2: quadrant (m4-7, n2-3)
    RDB8(boff, 2);
    BAR8(); LGKM0();
    MM8(4, 2);
    // phase 3: quadrant (m0-3, n2-3); stage A(t+2)-lo; counted vmcnt once per tile
    STAGE8(t + 2, 0);
    if (t < 30) {
      asm volatile("s_waitcnt vmcnt(2)" ::: "memory");
    } else if (t == 30) {
      asm volatile("s_waitcnt vmcnt(0)" ::: "memory");
    }
    BAR8(); LGKM0();
    MM8(0, 2);
  }
#undef STAGE8
#undef RDA8
#undef RDB8
#undef MM8
#undef BAR8
#undef LGKM0
}

// ---------------- fused QKV GEMM (C^T) + RMSNorm + RoPE + head scatter ----------------
__global__ __launch_bounds__(512) void gemm_qkv_fused(const u16* __restrict__ xb,
                                                      const u16* __restrict__ Wcat,
                                                      const float* __restrict__ freqs,
                                                      u16* __restrict__ qb, u16* __restrict__ kb,
                                                      u16* __restrict__ vb) {
  extern __shared__ char smem[];
  // T1 bijective XCD swizzle: nwg=384, cpx=48
  int bid = blockIdx.y * 12 + blockIdx.x;
  int swz = (bid & 7) * 48 + (bid >> 3);
  const int n0d = (swz % 12) * 256;   // qkv-dim offset (Q:<2048, K:2048..2560, V:>=2560)
  const int t0 = (swz / 12) * 256;    // token offset
  f32x4 acc[8][4] = {};
  core8(Wcat, xb, n0d, t0, smem, acc);

  const int tid = threadIdx.x;
  const int lane = tid & 63, w = tid >> 6;
  const int wm = w >> 2, wn = w & 3;
  const int quad = lane >> 4, lo = lane & 15;
  const int bb = t0 >> 11;            // batch (256-token tile never crosses batches)

  if (n0d >= 2560) {                  // ---- V: direct transposed store (vb = B*HKV, D, T) ----
    int head = ((n0d - 2560) >> 7) + wm;
    size_t vbase = (size_t)(bb * HKV_ + head) * D_ * T_;
#pragma unroll
    for (int n = 0; n < 4; n++) {
      int t = (t0 & 2047) + wn * 64 + n * 16 + lo;
#pragma unroll
      for (int m = 0; m < 8; m++) {
        int dd = m * 16 + quad * 4;
#pragma unroll
        for (int r = 0; r < 4; r++)
          vb[vbase + (size_t)(dd + r) * T_ + t] = f2bf(acc[m][n][r]);
      }
    }
    return;
  }

  // ---- Q/K: RMSNorm (in-wave: lane covers 32 of its head's 128 d, reduce over quads) ----
  const int isQ = (n0d < 2048) ? 1 : 0;
  const float qs = isQ ? 0.08838834764831845f : 1.0f;   // 1/sqrt(D) folded into q
  float ss[4] = {0.f, 0.f, 0.f, 0.f};
#pragma unroll
  for (int m = 0; m < 8; m++)
#pragma unroll
    for (int n = 0; n < 4; n++)
#pragma unroll
      for (int r = 0; r < 4; r++) ss[n] += acc[m][n][r] * acc[m][n][r];
#pragma unroll
  for (int n = 0; n < 4; n++) {
    ss[n] += __shfl_xor(ss[n], 16, 64);
    ss[n] += __shfl_xor(ss[n], 32, 64);
    ss[n] = rsqrtf(ss[n] * (1.0f / 128.0f) + 1e-6f) * qs;  // reuse as scale
  }

  // ---- RoPE + LDS transpose + store, one head (m-wave) at a time ----
  __syncthreads();                    // all waves past the K-loop before smem reuse
  u16* Tr = (u16*)smem;               // [256 tokens][136 d-stride] u16
  const int baseh = isQ ? (n0d >> 7) : ((n0d - 2048) >> 7);
  const int heads = isQ ? H_ : HKV_;
  u16* dst = isQ ? qb : kb;
#pragma unroll
  for (int hh = 0; hh < 2; hh++) {
    if (wm == hh) {
#pragma unroll
      for (int n = 0; n < 4; n++) {
        int tl = wn * 64 + n * 16 + lo;
        const float* fp = freqs + (size_t)((t0 & 2047) + tl) * 128;
#pragma unroll
        for (int m = 0; m < 8; m++) {
          float4 f = *(const float4*)(fp + m * 16 + quad * 4);
          float a0 = acc[m][n][0] * ss[n], a1 = acc[m][n][1] * ss[n];
          unsigned pk0 = (unsigned)f2bf(a0 * f.x - a1 * f.y) |
                         (((unsigned)f2bf(a0 * f.y + a1 * f.x)) << 16);
          float a2 = acc[m][n][2] * ss[n], a3 = acc[m][n][3] * ss[n];
          unsigned pk1 = (unsigned)f2bf(a2 * f.z - a3 * f.w) |
                         (((unsigned)f2bf(a2 * f.w + a3 * f.z)) << 16);
          int dd = m * 16 + quad * 4;
          *(unsigned*)(&Tr[tl * 136 + dd]) = pk0;
          *(unsigned*)(&Tr[tl * 136 + dd + 2]) = pk1;
        }
      }
    }
    __syncthreads();
    int head = baseh + hh;
    int ic = tid & 15, r0 = tid >> 4;
#pragma unroll
    for (int j = 0; j < 8; j++) {
      int tl = r0 + j * 32;
      int g = t0 + tl;
      int b = g >> 11, tt = g & 2047;
      uint4 v4 = *(const uint4*)(&Tr[tl * 136 + ic * 8]);
      *(uint4*)(&dst[((size_t)(b * heads + head) * T_ + tt) * D_ + ic * 8]) = v4;
    }
    __syncthreads();
  }
}

// ---------------- final projection: out(8192,2048) = yb(8192,2048) * WcT(2048,2048)^T ----------------
__global__ __launch_bounds__(512) void gemm_wc(const u16* __restrict__ yb,
                                               const u16* __restrict__ WcT,
                                               float* __restrict__ out) {
  extern __shared__ char smem[];
  // T1 swizzle: nwg=256, cpx=32
  int bid = blockIdx.y * 8 + blockIdx.x;
  int swz = (bid & 7) * 32 + (bid >> 3);
  const int n0 = (swz & 7) * 256, m0 = (swz >> 3) * 256;
  f32x4 acc[8][4] = {};
  core8(yb, WcT, m0, n0, smem, acc);

  const int tid = threadIdx.x;
  const int lane = tid & 63, w = tid >> 6;
  const int wm = w >> 2, wn = w & 3;
  const int quad = lane >> 4, lo = lane & 15;
#pragma unroll
  for (int m = 0; m < 8; m++)
#pragma unroll
    for (int n = 0; n < 4; n++)
#pragma unroll
      for (int r = 0; r < 4; r++) {
        int mg = m0 + wm * 128 + m * 16 + quad * 4 + r;
        int ng = n0 + wn * 64 + n * 16 + lo;
        out[(size_t)mg * 2048 + ng] = acc[m][n][r];
      }
}

// ---------------- Flash attention, causal, GQA, triangle-paired (unchanged from r2) ----------------
__global__ __launch_bounds__(256) void flash_kernel(const u16* __restrict__ qb, const u16* __restrict__ kb,
                                                    const u16* __restrict__ vb, u16* __restrict__ yb) {
  __shared__ __align__(16) u16 smem[32768];   // 2x Ks(64x128) + 2x Vs(128x64) = 64 KB
  int bh = blockIdx.x;
  int b = bh >> 4, hq = bh & 15;
  int jp = blockIdx.y;
  int tid = threadIdx.x, w = tid >> 6, lane = tid & 63;
  int half = lane >> 5, lq = lane & 31;
  int bhkv = b * HKV_ + (hq >> 2);
  const u16* kbase = kb + (size_t)bhkv * T_ * D_;
  const u16* vbase = vb + (size_t)bhkv * D_ * T_;
  const float L2E = 1.4426950408889634f;
  const float N12 = -17.312340490667562f;

  int kchunk = lane & 15, krow0 = w * 16 + (lane >> 4);
  int vchunk = lane & 7, vrow0 = w * 32 + (lane >> 3);

  for (int ph = 0; ph < 2; ph++) {
    int qt = ph ? jp : (15 - jp);
    const u16* qbase = qb + ((size_t)bh * T_ + qt * 128) * D_;
    int qwave = qt * 128 + w * 32;

    bf16x8 qf[8];
#pragma unroll
    for (int ds = 0; ds < 8; ds++)
      qf[ds] = *(const bf16x8*)(&qbase[(w * 32 + lq) * D_ + ds * 16 + half * 8]);

    f32x16 oacc[4] = {};
    float l_part = 0.f;

    int ktmax = 2 * qt + 1;

#define STAGEF(kt_)                                                                          \
    do {                                                                                     \
      const u16* ks_ = kbase + (size_t)((kt_) * 64) * D_;                                    \
      const u16* vs_ = vbase + (kt_) * 64;                                                   \
      u16* K_ = smem + (((kt_) & 1) << 13);                                                  \
      u16* V_ = smem + 16384 + (((kt_) & 1) << 13);                                          \
      _Pragma("unroll") for (int c_ = 0; c_ < 4; c_++) {                                     \
        int r_ = krow0 + c_ * 4;                                                             \
        async_cp16(&ks_[r_ * D_ + ((kchunk ^ (r_ & 7)) << 3)], &K_[r_ * 128 + (kchunk << 3)]);\
      }                                                                                      \
      _Pragma("unroll") for (int c_ = 0; c_ < 4; c_++) {                                     \
        int r_ = vrow0 + c_ * 8;                                                             \
        async_cp16(&vs_[(size_t)r_ * T_ + ((vchunk ^ (r_ & 7)) << 3)], &V_[r_ * 64 + (vchunk << 3)]);\
      }                                                                                      \
    } while (0)

    STAGEF(0);
    for (int kt = 0; kt <= ktmax; kt++) {
      if (kt < ktmax) {
        STAGEF(kt + 1);
        asm volatile("s_waitcnt vmcnt(8)" ::: "memory");   // wait buf[kt]'s 8 loads
      } else {
        asm volatile("s_waitcnt vmcnt(0)" ::: "memory");
      }
      __builtin_amdgcn_s_barrier();
      const u16* Ks = smem + ((kt & 1) << 13);
      const u16* Vs = smem + 16384 + ((kt & 1) << 13);

#pragma unroll
      for (int t = 0; t < 2; t++) {
        int k0 = kt * 64 + t * 32;
        if (k0 > qwave + 31) continue;

        f32x16 s = {}, sb = {};
        __builtin_amdgcn_s_setprio(1);
#pragma unroll
        for (int ds = 0; ds < 4; ds++) {
          bf16x8 kf = *(const bf16x8*)(&Ks[(t * 32 + lq) * 128 + ((((ds << 1) + half) ^ (lq & 7)) << 3)]);
          s = __builtin_amdgcn_mfma_f32_32x32x16_bf16(kf, qf[ds], s, 0, 0, 0);
        }
#pragma unroll
        for (int ds = 4; ds < 8; ds++) {
          bf16x8 kf = *(const bf16x8*)(&Ks[(t * 32 + lq) * 128 + ((((ds << 1) + half) ^ (lq & 7)) << 3)]);
          sb = __builtin_amdgcn_mfma_f32_32x32x16_bf16(kf, qf[ds], sb, 0, 0, 0);
        }
        __builtin_amdgcn_s_setprio(0);
        s = s + sb;

        int qglob = qwave + lq;
        if (k0 + 31 > qwave) {
#pragma unroll
          for (int i = 0; i < 16; i++) {
            int kl = k0 + 4 * half + (i & 3) + ((i >> 2) << 3);
            if (kl > qglob) s[i] = -1e30f;
          }
        }

        unsigned pd[8];
#pragma unroll
        for (int j2 = 0; j2 < 8; j2++) {
          float p0 = __builtin_amdgcn_exp2f(fmaf(s[2 * j2], L2E, N12));
          float p1 = __builtin_amdgcn_exp2f(fmaf(s[2 * j2 + 1], L2E, N12));
          l_part += p0 + p1;
          pd[j2] = __builtin_amdgcn_perm(__builtin_bit_cast(unsigned, p1),
                                         __builtin_bit_cast(unsigned, p0), 0x07060302u);
        }

        unsigned s0 = (unsigned)__shfl_xor((int)(half ? pd[0] : pd[2]), 32, 64);
        unsigned s1 = (unsigned)__shfl_xor((int)(half ? pd[1] : pd[3]), 32, 64);
        unsigned s2 = (unsigned)__shfl_xor((int)(half ? pd[4] : pd[6]), 32, 64);
        unsigned s3 = (unsigned)__shfl_xor((int)(half ? pd[5] : pd[7]), 32, 64);
        uint4 f0 = half ? uint4{s0, s1, pd[2], pd[3]} : uint4{pd[0], pd[1], s0, s1};
        uint4 f1 = half ? uint4{s2, s3, pd[6], pd[7]} : uint4{pd[4], pd[5], s2, s3};

        __builtin_amdgcn_s_setprio(1);
#pragma unroll
        for (int kstep = 0; kstep < 2; kstep++) {
          uint4 fr = kstep ? f1 : f0;
          bf16x8 pf = __builtin_bit_cast(bf16x8, fr);
          int cR = (t * 2 + kstep) * 2 + half;
#pragma unroll
          for (int dt = 0; dt < 4; dt++) {
            bf16x8 vf = *(const bf16x8*)(&Vs[(dt * 32 + lq) * 64 + ((cR ^ (lq & 7)) << 3)]);
            oacc[dt] = __builtin_amdgcn_mfma_f32_32x32x16_bf16(vf, pf, oacc[dt], 0, 0, 0);
          }
        }
        __builtin_amdgcn_s_setprio(0);
      }
      __builtin_amdgcn_s_barrier();
    }
#undef STAGEF

    float lt = l_part + __shfl_xor(l_part, 32, 64);
    float inv = 1.0f / lt;

    u16* Ep = smem;
#pragma unroll
    for (int dt = 0; dt < 4; dt++)
#pragma unroll
      for (int j2 = 0; j2 < 8; j2++) {
        float p0 = oacc[dt][2 * j2] * inv;
        float p1 = oacc[dt][2 * j2 + 1] * inv;
        unsigned pk = ((unsigned)f2bf(p0)) | (((unsigned)f2bf(p1)) << 16);
        int d = dt * 32 + 4 * half + 2 * (j2 & 1) + ((j2 >> 1) << 3);
        *(unsigned*)(&Ep[(w * 32 + lq) * 136 + d]) = pk;
      }
    __syncthreads();

    int ic = tid & 15, qr0 = tid >> 4;
    size_t orow = ((size_t)b * T_ + qt * 128) * 2048 + hq * 128;
#pragma unroll
    for (int j2 = 0; j2 < 8; j2++) {
      int qr = qr0 + j2 * 16;
      uint4 v4 = *(const uint4*)(&Ep[qr * 136 + ic * 8]);
      *(uint4*)(&yb[orow + (size_t)qr * 2048 + ic * 8]) = v4;
    }
    __syncthreads();
  }
}

extern "C" void kernel_launch(void* const* d_in, const int* in_sizes, int n_in,
                              void* d_out, int out_size, void* d_ws, size_t ws_size,
                              hipStream_t stream) {
  const float* x = (const float*)d_in[0];
  const float* freqs = (const float*)d_in[1];
  const float* Wq = (const float*)d_in[2];
  const float* Wk = (const float*)d_in[3];
  const float* Wv = (const float*)d_in[4];
  const float* Wc = (const float*)d_in[5];
  float* out = (float*)d_out;

  char* ws = (char*)d_ws;
  size_t off = 0;
  auto alloc = [&](size_t bytes) { char* p = ws + off; off += (bytes + 255) & ~255ull; return p; };
  u16* xb   = (u16*)alloc((size_t)B_ * T_ * C_ * 2);
  u16* Wcat = (u16*)alloc((size_t)C_ * 3072 * 2);
  u16* WcT  = (u16*)alloc((size_t)C_ * C_ * 2);
  u16* qb   = (u16*)alloc((size_t)B_ * H_ * T_ * D_ * 2);
  u16* kb   = (u16*)alloc((size_t)B_ * HKV_ * T_ * D_ * 2);
  u16* vb   = (u16*)alloc((size_t)B_ * HKV_ * T_ * D_ * 2);
  u16* yb   = (u16*)alloc((size_t)B_ * T_ * H_ * D_ * 2);

  static bool attr_done = false;
  if (!attr_done) {
    (void)hipFuncSetAttribute(reinterpret_cast<const void*>(gemm_qkv_fused),
                              hipFuncAttributeMaxDynamicSharedMemorySize, 131072);
    (void)hipFuncSetAttribute(reinterpret_cast<const void*>(gemm_wc),
                              hipFuncAttributeMaxDynamicSharedMemorySize, 131072);
    attr_done = true;
  }

  prep_kernel<<<dim3(4096 + 2560), dim3(256), 0, stream>>>(x, Wq, Wk, Wv, Wc, xb, Wcat, WcT);
  gemm_qkv_fused<<<dim3(12, 32), dim3(512), 131072, stream>>>(xb, Wcat, freqs, qb, kb, vb);
  flash_kernel<<<dim3(B_ * H_, 8), dim3(256), 0, stream>>>(qb, kb, vb, yb);
  gemm_wc<<<dim3(8, 32), dim3(512), 131072, stream>>>(yb, WcT, out);
}